// Round 5
// baseline (638.187 us; speedup 1.0000x reference)
//
#include <hip/hip_runtime.h>
#include <stdint.h>

#define B_DIM   8192
#define IN_DIM  1024
#define OUT_DIM 4096

using i32x4  = __attribute__((ext_vector_type(4)))  int;
using i32x8  = __attribute__((ext_vector_type(8)))  int;
using f32x16 = __attribute__((ext_vector_type(16))) float;

typedef const __attribute__((address_space(1))) char* gas_cp;
typedef __attribute__((address_space(3))) char*       las_p;

static __device__ __forceinline__ void gl2lds16(gas_cp g, las_p l) {
    __builtin_amdgcn_global_load_lds((const __attribute__((address_space(1))) void*)g,
                                     (__attribute__((address_space(3))) void*)l, 16, 0, 0);
}

// e2m1 code for v in [0,2.5): grid {0,0.5,1,1.5,2} -> enc {0,1,2,3,4}
// (v < 2.5 strictly since x < 1.2, so the 2.0/3.0 boundary at 2.5 never trips)
static __device__ __forceinline__ unsigned q_i(float v) {
    return (unsigned)(v >= 0.25f) + (unsigned)(v >= 0.75f)
         + (unsigned)(v >= 1.25f) + (unsigned)(v >= 1.75f);
}

// i = 2.5*clip(x-0.2,0)^2 quantized to fp4 e2m1 (scale 1.0), 8 nibbles/u32
__global__ __launch_bounds__(256) void prep_i(const float4* __restrict__ x4,
                                              unsigned* __restrict__ o, int n8) {
    int t = blockIdx.x * 256 + threadIdx.x;
    if (t >= n8) return;
    float4 u = x4[2 * t], v = x4[2 * t + 1];
    float a; unsigned r = 0;
    a = fmaxf(u.x - 0.2f, 0.f); r |= q_i(2.5f * a * a);
    a = fmaxf(u.y - 0.2f, 0.f); r |= q_i(2.5f * a * a) << 4;
    a = fmaxf(u.z - 0.2f, 0.f); r |= q_i(2.5f * a * a) << 8;
    a = fmaxf(u.w - 0.2f, 0.f); r |= q_i(2.5f * a * a) << 12;
    a = fmaxf(v.x - 0.2f, 0.f); r |= q_i(2.5f * a * a) << 16;
    a = fmaxf(v.y - 0.2f, 0.f); r |= q_i(2.5f * a * a) << 20;
    a = fmaxf(v.z - 0.2f, 0.f); r |= q_i(2.5f * a * a) << 24;
    a = fmaxf(v.w - 0.2f, 0.f); r |= q_i(2.5f * a * a) << 28;
    o[t] = r;
}

// wq = rint(w) in {-4..4}: exact in e2m1. |m| -> enc LUT {0,2,4,5,6}, sign -> bit3
static __device__ __forceinline__ unsigned q_w(float w) {
    float q = rintf(w);
    int m = (int)fabsf(q);
    unsigned e = (0x65420u >> (4 * m)) & 0xFu;
    return e | (q < 0.f ? 8u : 0u);
}

__global__ __launch_bounds__(256) void prep_w(const float4* __restrict__ w4,
                                              unsigned* __restrict__ o, int n8) {
    int t = blockIdx.x * 256 + threadIdx.x;
    if (t >= n8) return;
    float4 u = w4[2 * t], v = w4[2 * t + 1];
    unsigned r = 0;
    r |= q_w(u.x);       r |= q_w(u.y) << 4;
    r |= q_w(u.z) << 8;  r |= q_w(u.w) << 12;
    r |= q_w(v.x) << 16; r |= q_w(v.y) << 20;
    r |= q_w(v.z) << 24; r |= q_w(v.w) << 28;
    o[t] = r;
}

static __device__ __forceinline__ i32x8 w8(i32x4 v) {
    i32x8 r = { v[0], v[1], v[2], v[3], 0, 0, 0, 0 };
    return r;
}

// C-tile 128x128, 4 waves each 64x64 (2x2 of mfma_scale_32x32x64 fp4), stage=256k.
// Dual fp32 accumulators: acc_s += A*B(signed wq), acc_a += A*|B|;
// i_p=(a+s)/2, i_n=(a-s)/2. Scales pinned to 1.0 (0x7F E8M0).
// LDS XOR swizzle (R3/R4-verified zero-conflict): 128B rows of 8x16B granules,
// slot(row,g) = row*8 + (g ^ ((row>>1)&7)).
// __launch_bounds__(256,4): 4 blocks/CU (LDS 4x32=128<=160 KB, VGPR cap 128) —
// resident blocks' MFMA hides other blocks' per-stage vmcnt(0) barrier drain
// (at 2 blocks/CU the drain was exposed; m114 wave-level overlap is the fix).
__global__ __launch_bounds__(256, 4) void fused_gemm(
    const unsigned char* __restrict__ Aq,   // i  [8192][512B] fp4 nibbles
    const unsigned char* __restrict__ Wq,   // wq [4096][512B] fp4 nibbles
    float* __restrict__ out)                // [8192][4096] fp32
{
    __shared__ unsigned char As[128 * 128];  // 16 KB (128 rows x 256 k-nibbles)
    __shared__ unsigned char Bs[128 * 128];  // 16 KB

    const int t    = threadIdx.x;
    const int lane = t & 63;
    const int wv   = t >> 6;
    const int wm   = (wv >> 1) * 64;   // wave row offset in C-tile
    const int wn   = (wv & 1) * 64;    // wave col offset in C-tile
    const int rl   = lane & 31;
    const int g0   = lane >> 5;        // k-half selector (32 nibbles = 16B each)

    const int bm = blockIdx.y;         // batch / 128
    const int bn = blockIdx.x;         // out   / 128

    // staging: thread t fills phys slots {t + 256j}; slot s -> row s>>3,
    // logical granule (s&7) ^ ((s>>4)&7). Global row stride = 512 B (fp4).
    int goff[4];
#pragma unroll
    for (int j = 0; j < 4; ++j) {
        const int s = t + 256 * j;
        goff[j] = (s >> 3) * (IN_DIM / 2) + (((s & 7) ^ ((s >> 4) & 7)) * 16);
    }
    gas_cp gAb = (gas_cp)(const char*)Aq + (size_t)(bm * 128) * (IN_DIM / 2);
    gas_cp gBb = (gas_cp)(const char*)Wq + (size_t)(bn * 128) * (IN_DIM / 2);
    las_p  lA  = ((las_p)(char*)As) + t * 16;
    las_p  lB  = ((las_p)(char*)Bs) + t * 16;

    // fragment read offsets: phys = row*128 + ((g0 ^ h)*16 ^ ks*32), h=(row>>1)&7
    const int h     = (rl >> 1) & 7;
    const int pgb   = (g0 ^ h) * 16;
    const int offA0 = (wm + rl) * 128 + pgb;   // +32 rows -> +4096, h unchanged
    const int offB0 = (wn + rl) * 128 + pgb;

    const int SC1 = 0x7F7F7F7F;   // E8M0 scale = 1.0 in every byte

    f32x16 acc_s[2][2] = {};
    f32x16 acc_a[2][2] = {};

    for (int kb = 0; kb < IN_DIM / 2; kb += 128) {   // 4 stages of 256 k
#pragma unroll
        for (int j = 0; j < 4; ++j) {
            gl2lds16(gAb + goff[j] + kb, lA + j * 4096);
            gl2lds16(gBb + goff[j] + kb, lB + j * 4096);
        }
        __syncthreads();                             // drain gl2lds

#pragma unroll
        for (int ks = 0; ks < 4; ++ks) {             // 4 x K=64 per stage
            const int x = ks * 32;
            i32x4 a0 = *(const i32x4*)((const char*)As + (offA0 ^ x));
            i32x4 a1 = *(const i32x4*)((const char*)As + ((offA0 ^ x) + 4096));
            i32x4 b0 = *(const i32x4*)((const char*)Bs + (offB0 ^ x));
            i32x4 b1 = *(const i32x4*)((const char*)Bs + ((offB0 ^ x) + 4096));
            i32x8 A0 = w8(a0), A1 = w8(a1);
            i32x8 B0 = w8(b0), B1 = w8(b1);
            i32x8 P0 = w8(b0 & 0x77777777);          // fp4 |x|: clear nibble sign bits
            i32x8 P1 = w8(b1 & 0x77777777);

#define MF(acc, Av, Bv) acc = __builtin_amdgcn_mfma_scale_f32_32x32x64_f8f6f4( \
                              Av, Bv, acc, 4, 4, 0, SC1, 0, SC1)
            MF(acc_s[0][0], A0, B0);  MF(acc_a[0][0], A0, P0);
            MF(acc_s[1][0], A1, B0);  MF(acc_a[1][0], A1, P0);
            MF(acc_s[0][1], A0, B1);  MF(acc_a[0][1], A0, P1);
            MF(acc_s[1][1], A1, B1);  MF(acc_a[1][1], A1, P1);
#undef MF
        }
        __syncthreads();                             // protect LDS for next stage
    }

    // epilogue: 32x32 C/D layout col=lane&31, row=(reg&3)+8*(reg>>2)+4*(lane>>5).
    // Reference's own 1.2*(1-exp) form -> identical deep-tail rounding -> absmax 0.
#pragma unroll
    for (int mi = 0; mi < 2; ++mi) {
#pragma unroll
        for (int ni = 0; ni < 2; ++ni) {
            f32x16 s = acc_s[mi][ni];
            f32x16 a = acc_a[mi][ni];
            const int col = bn * 128 + wn + ni * 32 + rl;
#pragma unroll
            for (int r = 0; r < 16; ++r) {
                const int row = bm * 128 + wm + mi * 32 + (r & 3) + 8 * (r >> 2) + 4 * g0;
                float ip = 0.5f * (a[r] + s[r]);
                float in = 0.5f * (a[r] - s[r]);
                float gp = 1.2f * (1.0f - __expf(-0.05f * ip));
                float gn = 1.2f * (1.0f - __expf(-0.05f * in));
                out[(size_t)row * OUT_DIM + col] = gp - gn;
            }
        }
    }
}

extern "C" void kernel_launch(void* const* d_in, const int* in_sizes, int n_in,
                              void* d_out, int out_size, void* d_ws, size_t ws_size,
                              hipStream_t stream) {
    const float* x = (const float*)d_in[0];   // (8192, 1024)
    const float* w = (const float*)d_in[1];   // (4096, 1024)
    float* out = (float*)d_out;               // (8192, 4096)

    unsigned char* iq = (unsigned char*)d_ws;                    // 4 MB fp4
    unsigned char* wq = iq + (size_t)B_DIM * IN_DIM / 2;         // + 2 MB fp4

    const int n8i = B_DIM * IN_DIM / 8;       // 1,048,576
    prep_i<<<n8i / 256, 256, 0, stream>>>((const float4*)x, (unsigned*)iq, n8i);
    const int n8w = OUT_DIM * IN_DIM / 8;     // 524,288
    prep_w<<<n8w / 256, 256, 0, stream>>>((const float4*)w, (unsigned*)wq, n8w);

    dim3 grid(OUT_DIM / 128, B_DIM / 128);    // (32, 64)
    fused_gemm<<<grid, 256, 0, stream>>>(iq, wq, out);
}

// Round 6
// 191.628 us; speedup vs baseline: 3.3303x; 3.3303x over previous
//
#include <hip/hip_runtime.h>
#include <stdint.h>

#define B_DIM   8192
#define IN_DIM  1024
#define OUT_DIM 4096

using i32x4  = __attribute__((ext_vector_type(4)))  int;
using i32x8  = __attribute__((ext_vector_type(8)))  int;
using f32x16 = __attribute__((ext_vector_type(16))) float;

typedef const __attribute__((address_space(1))) char* gas_cp;
typedef __attribute__((address_space(3))) char*       las_p;

static __device__ __forceinline__ void gl2lds16(gas_cp g, las_p l) {
    __builtin_amdgcn_global_load_lds((const __attribute__((address_space(1))) void*)g,
                                     (__attribute__((address_space(3))) void*)l, 16, 0, 0);
}

// e2m1 code for v in [0,2.5): grid {0,0.5,1,1.5,2} -> enc {0,1,2,3,4}
static __device__ __forceinline__ unsigned q_i(float v) {
    return (unsigned)(v >= 0.25f) + (unsigned)(v >= 0.75f)
         + (unsigned)(v >= 1.25f) + (unsigned)(v >= 1.75f);
}

// i = 2.5*clip(x-0.2,0)^2 quantized to fp4 e2m1 (scale 1.0), 8 nibbles/u32
__global__ __launch_bounds__(256) void prep_i(const float4* __restrict__ x4,
                                              unsigned* __restrict__ o, int n8) {
    int t = blockIdx.x * 256 + threadIdx.x;
    if (t >= n8) return;
    float4 u = x4[2 * t], v = x4[2 * t + 1];
    float a; unsigned r = 0;
    a = fmaxf(u.x - 0.2f, 0.f); r |= q_i(2.5f * a * a);
    a = fmaxf(u.y - 0.2f, 0.f); r |= q_i(2.5f * a * a) << 4;
    a = fmaxf(u.z - 0.2f, 0.f); r |= q_i(2.5f * a * a) << 8;
    a = fmaxf(u.w - 0.2f, 0.f); r |= q_i(2.5f * a * a) << 12;
    a = fmaxf(v.x - 0.2f, 0.f); r |= q_i(2.5f * a * a) << 16;
    a = fmaxf(v.y - 0.2f, 0.f); r |= q_i(2.5f * a * a) << 20;
    a = fmaxf(v.z - 0.2f, 0.f); r |= q_i(2.5f * a * a) << 24;
    a = fmaxf(v.w - 0.2f, 0.f); r |= q_i(2.5f * a * a) << 28;
    o[t] = r;
}

// wq = rint(w) in {-4..4}: exact in e2m1. |m| -> enc LUT {0,2,4,5,6}, sign -> bit3
static __device__ __forceinline__ unsigned q_w(float w) {
    float q = rintf(w);
    int m = (int)fabsf(q);
    unsigned e = (0x65420u >> (4 * m)) & 0xFu;
    return e | (q < 0.f ? 8u : 0u);
}

__global__ __launch_bounds__(256) void prep_w(const float4* __restrict__ w4,
                                              unsigned* __restrict__ o, int n8) {
    int t = blockIdx.x * 256 + threadIdx.x;
    if (t >= n8) return;
    float4 u = w4[2 * t], v = w4[2 * t + 1];
    unsigned r = 0;
    r |= q_w(u.x);       r |= q_w(u.y) << 4;
    r |= q_w(u.z) << 8;  r |= q_w(u.w) << 12;
    r |= q_w(v.x) << 16; r |= q_w(v.y) << 20;
    r |= q_w(v.z) << 24; r |= q_w(v.w) << 28;
    o[t] = r;
}

static __device__ __forceinline__ i32x8 w8(i32x4 v) {
    i32x8 r = { v[0], v[1], v[2], v[3], 0, 0, 0, 0 };
    return r;
}

// C-tile 128x64, 4 waves in 2x2 grid, each 64x32 (2x1 of mfma_scale_32x32x64
// fp4), stage = 256 k-nibbles. Dual fp32 accumulators (acc_s: A*B, acc_a: A*|B|)
// = 4 x f32x16 = 64 regs -> total reg footprint ~120, fits __launch_bounds__
// (256,3) cap (~170) WITHOUT spill (R5 lesson: (256,4)+128-reg cap spilled the
// 128-reg accumulator set to scratch -> 2 GB scratch traffic, 9x regression).
// 3 blocks/CU x 24 KB LDS = 72 KB; 3 independent barrier groups/CU hide the
// per-stage vmcnt(0) drain that a single group exposes.
// LDS XOR swizzle (R3/R4-verified zero-conflict): 128B rows of 8x16B granules,
// slot(row,g) = row*8 + (g ^ ((row>>1)&7)); scales pinned to 1.0 (0x7F E8M0).
__global__ __launch_bounds__(256, 3) void fused_gemm(
    const unsigned char* __restrict__ Aq,   // i  [8192][512B] fp4 nibbles
    const unsigned char* __restrict__ Wq,   // wq [4096][512B] fp4 nibbles
    float* __restrict__ out)                // [8192][4096] fp32
{
    __shared__ unsigned char As[128 * 128];  // 16 KB
    __shared__ unsigned char Bs[64 * 128];   //  8 KB

    const int t    = threadIdx.x;
    const int lane = t & 63;
    const int wv   = t >> 6;
    const int wm   = (wv >> 1) * 64;   // wave row offset in C-tile (0 / 64)
    const int wn   = (wv & 1) * 32;    // wave col offset in C-tile (0 / 32)
    const int rl   = lane & 31;
    const int g0   = lane >> 5;        // k-half selector (32 nibbles = 16B)

    const int bm = blockIdx.y;         // batch / 128
    const int bn = blockIdx.x;         // out   / 64

    // staging slot s -> row = s>>3 (512B global stride), granule (s&7)^((s>>4)&7).
    // A: slots t+256j, j=0..3 (128 rows); B: slots t+256j, j=0..1 (64 rows).
    int goff[4];
#pragma unroll
    for (int j = 0; j < 4; ++j) {
        const int s = t + 256 * j;
        goff[j] = (s >> 3) * (IN_DIM / 2) + (((s & 7) ^ ((s >> 4) & 7)) * 16);
    }
    gas_cp gAb = (gas_cp)(const char*)Aq + (size_t)(bm * 128) * (IN_DIM / 2);
    gas_cp gBb = (gas_cp)(const char*)Wq + (size_t)(bn * 64) * (IN_DIM / 2);
    las_p  lA  = ((las_p)(char*)As) + t * 16;
    las_p  lB  = ((las_p)(char*)Bs) + t * 16;

    // fragment read offsets: phys = row*128 + ((g0 ^ h)*16 ^ ks*32), h=(row>>1)&7
    const int h     = (rl >> 1) & 7;
    const int pgb   = (g0 ^ h) * 16;
    const int offA0 = (wm + rl) * 128 + pgb;   // second m-tile at +4096
    const int offB0 = (wn + rl) * 128 + pgb;

    const int SC1 = 0x7F7F7F7F;   // E8M0 scale = 1.0 in every byte

    f32x16 acc_s[2] = {};
    f32x16 acc_a[2] = {};

    for (int kb = 0; kb < IN_DIM / 2; kb += 128) {   // 4 stages of 256 k
#pragma unroll
        for (int j = 0; j < 4; ++j)
            gl2lds16(gAb + goff[j] + kb, lA + j * 4096);
#pragma unroll
        for (int j = 0; j < 2; ++j)
            gl2lds16(gBb + goff[j] + kb, lB + j * 4096);
        __syncthreads();                             // drain gl2lds

#pragma unroll
        for (int ks = 0; ks < 4; ++ks) {             // 4 x K=64 per stage
            const int x = ks * 32;
            i32x4 a0 = *(const i32x4*)((const char*)As + (offA0 ^ x));
            i32x4 a1 = *(const i32x4*)((const char*)As + ((offA0 ^ x) + 4096));
            i32x4 b0 = *(const i32x4*)((const char*)Bs + (offB0 ^ x));
            i32x8 A0 = w8(a0), A1 = w8(a1);
            i32x8 B0 = w8(b0);
            i32x8 P0 = w8(b0 & 0x77777777);          // fp4 |x|: clear nibble signs

#define MF(acc, Av, Bv) acc = __builtin_amdgcn_mfma_scale_f32_32x32x64_f8f6f4( \
                              Av, Bv, acc, 4, 4, 0, SC1, 0, SC1)
            MF(acc_s[0], A0, B0);  MF(acc_a[0], A0, P0);
            MF(acc_s[1], A1, B0);  MF(acc_a[1], A1, P0);
#undef MF
        }
        __syncthreads();                             // protect LDS for next stage
    }

    // epilogue: 32x32 C/D layout col=lane&31, row=(reg&3)+8*(reg>>2)+4*(lane>>5).
    // Reference's own 1.2*(1-exp) form -> identical deep-tail rounding -> absmax 0.
    const int col = bn * 64 + wn + rl;
#pragma unroll
    for (int mi = 0; mi < 2; ++mi) {
        f32x16 s = acc_s[mi];
        f32x16 a = acc_a[mi];
#pragma unroll
        for (int r = 0; r < 16; ++r) {
            const int row = bm * 128 + wm + mi * 32 + (r & 3) + 8 * (r >> 2) + 4 * g0;
            float ip = 0.5f * (a[r] + s[r]);
            float in = 0.5f * (a[r] - s[r]);
            float gp = 1.2f * (1.0f - __expf(-0.05f * ip));
            float gn = 1.2f * (1.0f - __expf(-0.05f * in));
            out[(size_t)row * OUT_DIM + col] = gp - gn;
        }
    }
}

extern "C" void kernel_launch(void* const* d_in, const int* in_sizes, int n_in,
                              void* d_out, int out_size, void* d_ws, size_t ws_size,
                              hipStream_t stream) {
    const float* x = (const float*)d_in[0];   // (8192, 1024)
    const float* w = (const float*)d_in[1];   // (4096, 1024)
    float* out = (float*)d_out;               // (8192, 4096)

    unsigned char* iq = (unsigned char*)d_ws;                    // 4 MB fp4
    unsigned char* wq = iq + (size_t)B_DIM * IN_DIM / 2;         // + 2 MB fp4

    const int n8i = B_DIM * IN_DIM / 8;       // 1,048,576
    prep_i<<<n8i / 256, 256, 0, stream>>>((const float4*)x, (unsigned*)iq, n8i);
    const int n8w = OUT_DIM * IN_DIM / 8;     // 524,288
    prep_w<<<n8w / 256, 256, 0, stream>>>((const float4*)w, (unsigned*)wq, n8w);

    dim3 grid(OUT_DIM / 64, B_DIM / 128);     // (64, 64)
    fused_gemm<<<grid, 256, 0, stream>>>(iq, wq, out);
}

// Round 7
// 190.261 us; speedup vs baseline: 3.3543x; 1.0072x over previous
//
#include <hip/hip_runtime.h>
#include <stdint.h>

#define B_DIM   8192
#define IN_DIM  1024
#define OUT_DIM 4096

using i32x4  = __attribute__((ext_vector_type(4)))  int;
using i32x8  = __attribute__((ext_vector_type(8)))  int;
using f32x16 = __attribute__((ext_vector_type(16))) float;

typedef const __attribute__((address_space(1))) char* gas_cp;
typedef __attribute__((address_space(3))) char*       las_p;

static __device__ __forceinline__ void gl2lds16(gas_cp g, las_p l) {
    __builtin_amdgcn_global_load_lds((const __attribute__((address_space(1))) void*)g,
                                     (__attribute__((address_space(3))) void*)l, 16, 0, 0);
}

// e2m1 code for v in [0,2.5): grid {0,0.5,1,1.5,2} -> enc {0,1,2,3,4}
static __device__ __forceinline__ unsigned q_i(float v) {
    return (unsigned)(v >= 0.25f) + (unsigned)(v >= 0.75f)
         + (unsigned)(v >= 1.25f) + (unsigned)(v >= 1.75f);
}

// wq = rint(w) in {-4..4}: exact in e2m1. |m| -> enc LUT {0,2,4,5,6}, sign -> bit3
static __device__ __forceinline__ unsigned q_w(float w) {
    float q = rintf(w);
    int m = (int)fabsf(q);
    unsigned e = (0x65420u >> (4 * m)) & 0xFu;
    return e | (q < 0.f ? 8u : 0u);
}

#define N8I (B_DIM * IN_DIM / 8)     // 1,048,576 u32 outputs for i
#define N8W (OUT_DIM * IN_DIM / 8)   //   524,288 u32 outputs for w

// fused prep: blocks [0, N8I/256) quantize i, the rest quantize w (one dispatch)
__global__ __launch_bounds__(256) void prep_all(const float4* __restrict__ x4,
                                                const float4* __restrict__ w4,
                                                unsigned* __restrict__ oi,
                                                unsigned* __restrict__ ow) {
    int b = blockIdx.x;
    if (b < N8I / 256) {
        int t = b * 256 + threadIdx.x;
        float4 u = x4[2 * t], v = x4[2 * t + 1];
        float a; unsigned r = 0;
        a = fmaxf(u.x - 0.2f, 0.f); r |= q_i(2.5f * a * a);
        a = fmaxf(u.y - 0.2f, 0.f); r |= q_i(2.5f * a * a) << 4;
        a = fmaxf(u.z - 0.2f, 0.f); r |= q_i(2.5f * a * a) << 8;
        a = fmaxf(u.w - 0.2f, 0.f); r |= q_i(2.5f * a * a) << 12;
        a = fmaxf(v.x - 0.2f, 0.f); r |= q_i(2.5f * a * a) << 16;
        a = fmaxf(v.y - 0.2f, 0.f); r |= q_i(2.5f * a * a) << 20;
        a = fmaxf(v.z - 0.2f, 0.f); r |= q_i(2.5f * a * a) << 24;
        a = fmaxf(v.w - 0.2f, 0.f); r |= q_i(2.5f * a * a) << 28;
        oi[t] = r;
    } else {
        int t = (b - N8I / 256) * 256 + threadIdx.x;
        float4 u = w4[2 * t], v = w4[2 * t + 1];
        unsigned r = 0;
        r |= q_w(u.x);       r |= q_w(u.y) << 4;
        r |= q_w(u.z) << 8;  r |= q_w(u.w) << 12;
        r |= q_w(v.x) << 16; r |= q_w(v.y) << 20;
        r |= q_w(v.z) << 24; r |= q_w(v.w) << 28;
        ow[t] = r;
    }
}

static __device__ __forceinline__ i32x8 w8(i32x4 v) {
    i32x8 r = { v[0], v[1], v[2], v[3], 0, 0, 0, 0 };
    return r;
}

// C-tile 128x64, 4 waves (2x2), each 64x32 = 2x1 of mfma_scale_32x32x64 fp4.
// Dual fp32 acc (acc_s: A*B signed, acc_a: A*|B|); i_p=(a+s)/2, i_n=(a-s)/2.
// DOUBLE-BUFFERED LDS, prefetch-AFTER-barrier: each phase = [barrier (drains
// stage-k loads, issued a full compute-phase ago -> ~free; also fences the
// buffer being overwritten), issue stage-k+1 gl2lds into other buffer,
// compute stage k]. Inputs are L2-resident (6 MB), load latency ~200 cyc <<
// 560-cyc MFMA phase -> drain hidden. 48 KB LDS x 3 blocks/CU = 144 <= 160.
// (256,3): reg footprint ~120 < cap ~170 — no spill (R5 cliff avoided).
// LDS XOR swizzle (R3/R4-verified zero-conflict): 128B rows of 8x16B granules,
// slot(row,g) = row*8 + (g ^ ((row>>1)&7)); scales pinned to 1.0 (0x7F E8M0).
__global__ __launch_bounds__(256, 3) void fused_gemm(
    const unsigned char* __restrict__ Aq,   // i  [8192][512B] fp4 nibbles
    const unsigned char* __restrict__ Wq,   // wq [4096][512B] fp4 nibbles
    float* __restrict__ out)                // [8192][4096] fp32
{
    __shared__ unsigned char As[2][128 * 128];  // 2 x 16 KB
    __shared__ unsigned char Bs[2][64 * 128];   // 2 x  8 KB

    const int t    = threadIdx.x;
    const int lane = t & 63;
    const int wv   = t >> 6;
    const int wm   = (wv >> 1) * 64;   // wave row offset in C-tile (0 / 64)
    const int wn   = (wv & 1) * 32;    // wave col offset in C-tile (0 / 32)
    const int rl   = lane & 31;
    const int g0   = lane >> 5;        // k-half selector (32 nibbles = 16B)

    const int bm = blockIdx.y;         // batch / 128
    const int bn = blockIdx.x;         // out   / 64

    // staging slot s -> row = s>>3 (512B global stride), granule (s&7)^((s>>4)&7)
    int goff[4];
#pragma unroll
    for (int j = 0; j < 4; ++j) {
        const int s = t + 256 * j;
        goff[j] = (s >> 3) * (IN_DIM / 2) + (((s & 7) ^ ((s >> 4) & 7)) * 16);
    }
    gas_cp gAb = (gas_cp)(const char*)Aq + (size_t)(bm * 128) * (IN_DIM / 2);
    gas_cp gBb = (gas_cp)(const char*)Wq + (size_t)(bn * 64) * (IN_DIM / 2);

    // fragment read offsets: phys = row*128 + ((g0 ^ h)*16 ^ ks*32), h=(row>>1)&7
    const int h     = (rl >> 1) & 7;
    const int pgb   = (g0 ^ h) * 16;
    const int offA0 = (wm + rl) * 128 + pgb;   // second m-tile at +4096
    const int offB0 = (wn + rl) * 128 + pgb;

    const int SC1 = 0x7F7F7F7F;   // E8M0 scale = 1.0 in every byte

    f32x16 acc_s[2] = {};
    f32x16 acc_a[2] = {};

    // stage kb (0..3) -> LDS buffer buf
    auto LD = [&](int kb, int buf) {
        las_p lA = ((las_p)(char*)As[buf]) + t * 16;
        las_p lB = ((las_p)(char*)Bs[buf]) + t * 16;
        const int kbyte = kb * 128;
#pragma unroll
        for (int j = 0; j < 4; ++j)
            gl2lds16(gAb + goff[j] + kbyte, lA + j * 4096);
#pragma unroll
        for (int j = 0; j < 2; ++j)
            gl2lds16(gBb + goff[j] + kbyte, lB + j * 4096);
    };

    auto CMP = [&](int buf) {
        const char* bA = (const char*)As[buf];
        const char* bB = (const char*)Bs[buf];
#pragma unroll
        for (int ks = 0; ks < 4; ++ks) {          // 4 x K=64 per stage
            const int x = ks * 32;
            i32x4 a0 = *(const i32x4*)(bA + (offA0 ^ x));
            i32x4 a1 = *(const i32x4*)(bA + ((offA0 ^ x) + 4096));
            i32x4 b0 = *(const i32x4*)(bB + (offB0 ^ x));
            i32x8 A0 = w8(a0), A1 = w8(a1);
            i32x8 B0 = w8(b0);
            i32x8 P0 = w8(b0 & 0x77777777);       // fp4 |x|: clear nibble signs

#define MF(acc, Av, Bv) acc = __builtin_amdgcn_mfma_scale_f32_32x32x64_f8f6f4( \
                              Av, Bv, acc, 4, 4, 0, SC1, 0, SC1)
            MF(acc_s[0], A0, B0);  MF(acc_a[0], A0, P0);
            MF(acc_s[1], A1, B0);  MF(acc_a[1], A1, P0);
#undef MF
        }
    };

    LD(0, 0);
    __syncthreads();  LD(1, 1);  CMP(0);
    __syncthreads();  LD(2, 0);  CMP(1);
    __syncthreads();  LD(3, 1);  CMP(0);
    __syncthreads();             CMP(1);

    // epilogue: 32x32 C/D layout col=lane&31, row=(reg&3)+8*(reg>>2)+4*(lane>>5).
    // Reference's own 1.2*(1-exp) form -> identical deep-tail rounding -> absmax 0.
    const int col = bn * 64 + wn + rl;
#pragma unroll
    for (int mi = 0; mi < 2; ++mi) {
        f32x16 s = acc_s[mi];
        f32x16 a = acc_a[mi];
#pragma unroll
        for (int r = 0; r < 16; ++r) {
            const int row = bm * 128 + wm + mi * 32 + (r & 3) + 8 * (r >> 2) + 4 * g0;
            float ip = 0.5f * (a[r] + s[r]);
            float in = 0.5f * (a[r] - s[r]);
            float gp = 1.2f * (1.0f - __expf(-0.05f * ip));
            float gn = 1.2f * (1.0f - __expf(-0.05f * in));
            out[(size_t)row * OUT_DIM + col] = gp - gn;
        }
    }
}

extern "C" void kernel_launch(void* const* d_in, const int* in_sizes, int n_in,
                              void* d_out, int out_size, void* d_ws, size_t ws_size,
                              hipStream_t stream) {
    const float* x = (const float*)d_in[0];   // (8192, 1024)
    const float* w = (const float*)d_in[1];   // (4096, 1024)
    float* out = (float*)d_out;               // (8192, 4096)

    unsigned char* iq = (unsigned char*)d_ws;                    // 4 MB fp4
    unsigned char* wq = iq + (size_t)B_DIM * IN_DIM / 2;         // + 2 MB fp4

    prep_all<<<N8I / 256 + N8W / 256, 256, 0, stream>>>(
        (const float4*)x, (const float4*)w, (unsigned*)iq, (unsigned*)wq);

    dim3 grid(OUT_DIM / 64, B_DIM / 128);     // (64, 64)
    fused_gemm<<<grid, 256, 0, stream>>>(iq, wq, out);
}